// Round 8
// baseline (151.928 us; speedup 1.0000x reference)
//
#include <hip/hip_runtime.h>

// Round 16: attn restructured for 4 blocks/CU occupancy.
//  - wave = 32 q-cols x full 64-kr chunk (two sequential 32-kr halves,
//    registers reused) -> state ~halved vs r15 (acc 32, S 16, bq 16).
//    LB(256,4) caps at 128 VGPR (incl AGPR) -> 4 blocks/CU; split=8
//    (grid 1024) so the grid delivers it. No wk-split -> no cross-wave
//    combine, no duplicated K/V reads.
//  - T12 in-register softmax (cvt_pk + permlane32_swap, r15-verified).
//  - per-wave LDS-transpose epilogue -> coalesced 1KB stores.
//  - proj: r13 fused QKV. prep/reduce unchanged.

typedef __bf16 bf16;
typedef __bf16 bf16x4 __attribute__((ext_vector_type(4)));
typedef __bf16 bf16x8 __attribute__((ext_vector_type(8)));
typedef float  f32x16 __attribute__((ext_vector_type(16)));

#define MFMA(a, b, c) __builtin_amdgcn_mfma_f32_32x32x16_bf16(a, b, c, 0, 0, 0)

constexpr int T = 4096, D = 1024, HS = 64;
constexpr int ROWS = 4 * T;                   // 16384
constexpr float QSCL = 0.045084220027797f;    // (1/32) * log2(e)

__device__ __forceinline__ void gld16(const void* g, void* l) {
    __builtin_amdgcn_global_load_lds(
        (const __attribute__((address_space(1))) unsigned int*)g,
        (__attribute__((address_space(3))) unsigned int*)l, 16, 0, 0);
}

__device__ inline f32x16 zero16() {
    f32x16 z;
#pragma unroll
    for (int i = 0; i < 16; ++i) z[i] = 0.f;
    return z;
}

// ---- prep: Wt[192][1024] bf16 = concat(Wq^T*QSCL, Wk^T, Wv^T) ----
__global__ __launch_bounds__(256) void prep_wt(
    const float* __restrict__ Wq, const float* __restrict__ Wk,
    const float* __restrict__ Wv, bf16* __restrict__ Wt)
{
    __shared__ float Xf[64 * 68];
    const int m = blockIdx.x >> 4, dt = blockIdx.x & 15;
    const float* W = (m == 0) ? Wq : ((m == 1) ? Wk : Wv);
    const int d0 = dt * 64;
#pragma unroll
    for (int j = 0; j < 4; ++j) {
        int i = threadIdx.x + 256 * j;
        int dr = i >> 4, c4 = i & 15;
        float4 v = *(const float4*)(W + (size_t)(d0 + dr) * 64 + c4 * 4);
        *(float4*)&Xf[dr * 68 + c4 * 4] = v;
    }
    __syncthreads();
    const float scl = (m == 0) ? QSCL : 1.0f;
#pragma unroll
    for (int j = 0; j < 4; ++j) {
        int o = threadIdx.x + 256 * j;
        int h = o >> 4, dc = o & 15;
        bf16x4 w;
#pragma unroll
        for (int k = 0; k < 4; ++k) w[k] = (bf16)(Xf[(dc * 4 + k) * 68 + h] * scl);
        *(bf16x4*)(Wt + (size_t)(m * 64 + h) * D + d0 + dc * 4) = w;
    }
}

// ---- fused projection: grid 256 = 8 xcd x 32 mtile; Q+K+V per block ----
__global__ __launch_bounds__(256) void qkv_proj(
    const float* __restrict__ x, const bf16* __restrict__ Wt,
    bf16* __restrict__ Qg, bf16* __restrict__ Kgt, bf16* __restrict__ Vgt)
{
    __shared__ __align__(16) bf16  Xb[2][64 * 64];   // swizzled granule: [r][u^(r&7)]
    __shared__ __align__(16) short Ws[2][192 * 64];  // swizzled: [h][u^(h&7)]
    const int tid = threadIdx.x;
    const int w = tid >> 6, lane = tid & 63, ln5 = lane & 31, hi = lane >> 5;
    const int tt = w & 1, hh = w >> 1;
    const int xcd = blockIdx.x & 7, mlocal = blockIdx.x >> 3;
    const int r0 = (xcd * 32 + mlocal) * 64;
    const int wb = tid & 448;

    auto stageW = [&](int kc, int buf) {
#pragma unroll
        for (int k2 = 0; k2 < 6; ++k2) {
            int s = k2 * 256 + tid;
            int h = s >> 3, j = s & 7, u = j ^ (h & 7);
            gld16(Wt + (size_t)h * D + kc * 64 + u * 8,
                  &Ws[buf][(k2 * 256 + wb) * 8]);
        }
    };
    float4 xra[2], xrb[2];
    auto stageX_load = [&](int kc) {
#pragma unroll
        for (int k = 0; k < 2; ++k) {
            int e = k * 256 + tid;
            int r = e >> 3, d0 = (e & 7) * 8;
            const float* src = x + (size_t)(r0 + r) * D + kc * 64 + d0;
            xra[k] = *(const float4*)src;
            xrb[k] = *(const float4*)(src + 4);
        }
    };
    auto stageX_write = [&](int buf) {
#pragma unroll
        for (int k = 0; k < 2; ++k) {
            int e = k * 256 + tid;
            int r = e >> 3, d0 = (e & 7) * 8;
            bf16x8 v;
            v[0] = (bf16)xra[k].x; v[1] = (bf16)xra[k].y;
            v[2] = (bf16)xra[k].z; v[3] = (bf16)xra[k].w;
            v[4] = (bf16)xrb[k].x; v[5] = (bf16)xrb[k].y;
            v[6] = (bf16)xrb[k].z; v[7] = (bf16)xrb[k].w;
            *(bf16x8*)&Xb[buf][r * 64 + (((d0 >> 3) ^ (r & 7)) * 8)] = v;
        }
    };

    f32x16 acc0 = zero16(), acc1 = zero16(), acc2 = zero16();
    const int rx = tt * 32 + ln5;
    const int hq = hh * 32 + ln5;
    const int swz = ln5 & 7;

    stageX_load(0); stageW(0, 0); stageX_write(0);
    __syncthreads();
    for (int kc = 0; kc < 16; ++kc) {
        const int cur = kc & 1;
        if (kc < 15) { stageW(kc + 1, cur ^ 1); stageX_load(kc + 1); }
        const bf16*  Xc = &Xb[cur][0];
        const short* Wb = &Ws[cur][0];
#pragma unroll
        for (int ks = 0; ks < 4; ++ks) {
            int g = (ks * 2 + hi) ^ swz;
            bf16x8 fx = *(const bf16x8*)&Xc[rx * 64 + g * 8];
            bf16x8 w0 = *(const bf16x8*)&Wb[(hq)       * 64 + g * 8];
            bf16x8 w1 = *(const bf16x8*)&Wb[(64 + hq)  * 64 + g * 8];
            bf16x8 w2 = *(const bf16x8*)&Wb[(128 + hq) * 64 + g * 8];
            acc0 = MFMA(w0, fx, acc0);   // Q: C^T (col = t)
            acc1 = MFMA(w1, fx, acc1);   // K: C^T (col = t)
            acc2 = MFMA(fx, w2, acc2);   // V: C   (col = h)
        }
        if (kc < 15) stageX_write(cur ^ 1);
        __syncthreads();
    }

    {
        int t = r0 + tt * 32 + ln5;
#pragma unroll
        for (int g = 0; g < 4; ++g) {
            int h0 = hh * 32 + 8 * g + 4 * hi;
            bf16x4 v;
#pragma unroll
            for (int k = 0; k < 4; ++k) v[k] = (bf16)acc0[4 * g + k];
            *(bf16x4*)(Qg + (size_t)t * HS + h0) = v;
        }
    }
    {
        int t = r0 + tt * 32 + ln5;
#pragma unroll
        for (int g = 0; g < 4; ++g) {
            int h0 = hh * 32 + 8 * g + 4 * hi;
            bf16x4 v;
#pragma unroll
            for (int k = 0; k < 4; ++k) v[k] = (bf16)acc1[4 * g + k];
            int j = (h0 >> 3) ^ (t & 7);
            *(bf16x4*)(Kgt + (size_t)t * HS + j * 8 + 4 * hi) = v;
        }
    }
    {
        int hr = hh * 32 + ln5;
#pragma unroll
        for (int g = 0; g < 4; ++g) {
            int t0 = tt * 32 + 8 * g + 4 * hi;
            bf16x4 v;
#pragma unroll
            for (int k = 0; k < 4; ++k) v[k] = (bf16)acc2[4 * g + k];
            int j = (t0 >> 3) ^ (hr & 7);
            *(bf16x4*)(Vgt + (size_t)r0 * HS + hr * 64 + j * 8 + 4 * hi) = v;
        }
    }
}

// ---- attention: block = 128 q-rows = 4 waves x 32 q; wave owns full kr ----
// 4 blocks/CU (LB cap 128 regs). Zero-LDS k-loop, per-wave epilogue.
__global__ __launch_bounds__(256, 4) void attn(
    const bf16* __restrict__ Qg, const bf16* __restrict__ Kgt,
    const bf16* __restrict__ Vgt, float* __restrict__ Op,
    float* __restrict__ Lp, float* __restrict__ out, int split)
{
    __shared__ __align__(16) float OX[4][2208];      // per-wave [32 q][68] + 32 l

    const int tid = threadIdx.x;
    const int w = tid >> 6, lane = tid & 63, ln5 = lane & 31, hi = lane >> 5;

    int b, qt, half;
    if (split == 8) {
        int rest = blockIdx.x >> 3; qt = rest & 31;
        int combo = (blockIdx.x & 7) + 8 * (rest >> 5);   // [0,32): (b,half)/XCD
        b = combo >> 3; half = combo & 7;
    } else if (split == 4) {
        int rest = blockIdx.x >> 3; qt = rest & 31;
        int combo = (blockIdx.x & 7) + 8 * (rest >> 5);
        b = combo >> 2; half = combo & 3;
    } else if (split == 2) {
        int c2 = blockIdx.x & 7; b = c2 >> 1; half = c2 & 1; qt = blockIdx.x >> 3;
    } else { b = blockIdx.x & 3; half = 0; qt = blockIdx.x >> 2; }

    const int rbase = b * T;
    const int seg = T / split;
    const int kb0 = rbase + half * seg;
    const int nc = seg / 64;
    const int qrow0 = rbase + qt * 128 + w * 32;     // wave's 32 q rows

    // Q B-frags for the wave's 32 q-cols (d = 0..63)
    bf16x8 bq[4];
    {
        const bf16* qp = Qg + (size_t)(qrow0 + ln5) * HS + hi * 8;
#pragma unroll
        for (int ks = 0; ks < 4; ++ks)
            bq[ks] = *(const bf16x8*)(qp + ks * 16);
    }

    const bf16* Kc = Kgt + (size_t)kb0 * HS;
    const bf16* Vc = Vgt + (size_t)kb0 * HS;

    f32x16 O0 = zero16(), O1 = zero16();
    float l0 = 0.f;
    const int swz = ln5 & 7;
    int ko[2][4], ku[2][2];
#pragma unroll
    for (int h = 0; h < 2; ++h) {
#pragma unroll
        for (int k = 0; k < 4; ++k)
            ko[h][k] = (h * 32 + ln5) * 64 + ((2 * k + hi) ^ swz) * 8;
#pragma unroll
        for (int ks = 0; ks < 2; ++ks)
            ku[h][ks] = ((h * 4 + ks * 2 + hi) ^ swz) * 8;
    }
    const int vr0 = ln5 * 64, vr1 = (32 + ln5) * 64;

    union U8 { unsigned u[4]; bf16x8 v; };

    for (int c = 0; c < nc; ++c) {
        const bf16* Kb = Kc + (size_t)c * 4096;
        const bf16* Vb = Vc + (size_t)c * 4096;
#pragma unroll
        for (int h = 0; h < 2; ++h) {
            bf16x8 kf0 = *(const bf16x8*)(Kb + ko[h][0]);
            bf16x8 kf1 = *(const bf16x8*)(Kb + ko[h][1]);
            bf16x8 kf2 = *(const bf16x8*)(Kb + ko[h][2]);
            bf16x8 kf3 = *(const bf16x8*)(Kb + ko[h][3]);
            bf16x8 v00 = *(const bf16x8*)(Vb + vr0 + ku[h][0]);
            bf16x8 v01 = *(const bf16x8*)(Vb + vr0 + ku[h][1]);
            bf16x8 v10 = *(const bf16x8*)(Vb + vr1 + ku[h][0]);
            bf16x8 v11 = *(const bf16x8*)(Vb + vr1 + ku[h][1]);

            // S^T = K_half * Q^T  (32 kr x 32 q)
            f32x16 S = zero16();
            S = MFMA(kf0, bq[0], S);
            S = MFMA(kf1, bq[1], S);
            S = MFMA(kf2, bq[2], S);
            S = MFMA(kf3, bq[3], S);

            // no-max softmax; pack P^T bf16 in-register (T12)
            unsigned wa[8];
#pragma unroll
            for (int g = 0; g < 4; ++g) {
                float p0 = __builtin_amdgcn_exp2f(S[4 * g + 0]);
                float p1 = __builtin_amdgcn_exp2f(S[4 * g + 1]);
                float p2 = __builtin_amdgcn_exp2f(S[4 * g + 2]);
                float p3 = __builtin_amdgcn_exp2f(S[4 * g + 3]);
                l0 += (p0 + p1) + (p2 + p3);
                asm("v_cvt_pk_bf16_f32 %0, %1, %2" : "=v"(wa[2 * g])     : "v"(p0), "v"(p1));
                asm("v_cvt_pk_bf16_f32 %0, %1, %2" : "=v"(wa[2 * g + 1]) : "v"(p2), "v"(p3));
            }
#pragma unroll
            for (int j = 0; j < 2; ++j) {
                asm("v_permlane32_swap_b32 %0, %1" : "+v"(wa[j]),     "+v"(wa[j + 2]));
                asm("v_permlane32_swap_b32 %0, %1" : "+v"(wa[4 + j]), "+v"(wa[6 + j]));
            }
            U8 fa0, fa1;
            fa0.u[0] = wa[0]; fa0.u[1] = wa[1]; fa0.u[2] = wa[2]; fa0.u[3] = wa[3];
            fa1.u[0] = wa[4]; fa1.u[1] = wa[5]; fa1.u[2] = wa[6]; fa1.u[3] = wa[7];

            // O^T += V^T_half * P^T
            O0 = MFMA(v00, fa0.v, O0);
            O1 = MFMA(v10, fa0.v, O1);
            O0 = MFMA(v01, fa1.v, O0);
            O1 = MFMA(v11, fa1.v, O1);
        }
    }

    l0 += __shfl_xor(l0, 32, 64);

    // per-wave LDS transpose -> coalesced stores (no cross-wave sync needed)
    float* Os = &OX[w][0];                           // [32 q][68]
    float* Ls = &OX[w][32 * 68];
#pragma unroll
    for (int g = 0; g < 4; ++g) {
        int h0 = 8 * g + 4 * hi;
        float4 a, bb;
        a.x  = O0[4 * g + 0]; a.y  = O0[4 * g + 1];
        a.z  = O0[4 * g + 2]; a.w  = O0[4 * g + 3];
        bb.x = O1[4 * g + 0]; bb.y = O1[4 * g + 1];
        bb.z = O1[4 * g + 2]; bb.w = O1[4 * g + 3];
        *(float4*)&Os[ln5 * 68 + h0]      = a;       // h-tile 0
        *(float4*)&Os[ln5 * 68 + 32 + h0] = bb;      // h-tile 1
    }
    if (hi == 0) Ls[ln5] = l0;

    if (split == 1) {
#pragma unroll
        for (int j = 0; j < 8; ++j) {
            int q = 4 * j + (lane >> 4), i = lane & 15;
            float4 v = *(const float4*)&Os[q * 68 + i * 4];
            float inv = 1.0f / Ls[q];
            v.x *= inv; v.y *= inv; v.z *= inv; v.w *= inv;
            *(float4*)(out + (size_t)(qrow0 + q) * HS + i * 4) = v;
        }
    } else {
        float* Od = Op + (size_t)half * ROWS * HS;
#pragma unroll
        for (int j = 0; j < 8; ++j) {
            int q = 4 * j + (lane >> 4), i = lane & 15;
            float4 v = *(const float4*)&Os[q * 68 + i * 4];
            *(float4*)(Od + (size_t)(qrow0 + q) * HS + i * 4) = v;
        }
        if (hi == 0) Lp[half * ROWS + qrow0 + ln5] = l0;
    }
}

// ---- reduce: out = sum_h(O_h) / sum_h(l_h) ----
__global__ __launch_bounds__(256) void attn_reduce(
    const float* __restrict__ Op, const float* __restrict__ Lp,
    float* __restrict__ out, int split)
{
    int idx = blockIdx.x * 256 + threadIdx.x;        // float4 index
    int row = idx >> 4;
    float4 s; s.x = s.y = s.z = s.w = 0.f;
    float lsum = 0.f;
    for (int h = 0; h < split; ++h) {
        float4 a = *(const float4*)(Op + (size_t)h * ROWS * HS + (size_t)idx * 4);
        s.x += a.x; s.y += a.y; s.z += a.z; s.w += a.w;
        lsum += Lp[h * ROWS + row];
    }
    float inv = 1.0f / lsum;
    s.x *= inv; s.y *= inv; s.z *= inv; s.w *= inv;
    *(float4*)(out + (size_t)idx * 4) = s;
}

extern "C" void kernel_launch(void* const* d_in, const int* in_sizes, int n_in,
                              void* d_out, int out_size, void* d_ws, size_t ws_size,
                              hipStream_t stream)
{
    const float* x  = (const float*)d_in[0];
    const float* Wq = (const float*)d_in[1];
    const float* Wk = (const float*)d_in[2];
    const float* Wv = (const float*)d_in[3];
    float* out = (float*)d_out;

    char* ws = (char*)d_ws;
    bf16* Qg  = (bf16*)(ws);                          // 2 MB  [16384][64]
    bf16* Kgt = (bf16*)(ws + ((size_t)2 << 20));      // 2 MB  tiled+swizzled
    bf16* Vgt = (bf16*)(ws + ((size_t)4 << 20));      // 2 MB  tiled+swizzled
    bf16* Wt  = (bf16*)(ws + ((size_t)6 << 20));      // 384 KB [192][1024]
    float* Lp = (float*)(ws + ((size_t)6 << 20));     // 512 KB max (overlays Wt)
    float* Op = (float*)(ws + ((size_t)6 << 20) + ((size_t)1 << 19));

    const size_t base = ((size_t)6 << 20) + ((size_t)1 << 19);
    int split = 1;
    if (ws_size >= base + (size_t)8 * ROWS * HS * sizeof(float)) split = 8;
    else if (ws_size >= base + (size_t)4 * ROWS * HS * sizeof(float)) split = 4;
    else if (ws_size >= base + (size_t)2 * ROWS * HS * sizeof(float)) split = 2;

    prep_wt<<<48, 256, 0, stream>>>(Wq, Wk, Wv, Wt);
    qkv_proj<<<256, 256, 0, stream>>>(x, Wt, Qg, Kgt, Vgt);
    attn<<<128 * split, 256, 0, stream>>>(Qg, Kgt, Vgt, Op, Lp, out, split);
    if (split > 1)
        attn_reduce<<<(ROWS * HS / 4) / 256, 256, 0, stream>>>(Op, Lp, out, split);
}

// Round 9
// 143.651 us; speedup vs baseline: 1.0576x; 1.0576x over previous
//
#include <hip/hip_runtime.h>

// Round 17: fragment-order K/V layouts -> perfectly coalesced attn k-loop.
//  Theory: attn is memory-TRANSACTION-bound: per-lane 16B fragment loads at
//  128B row stride touch 32 cache lines per wave instruction (25% line use).
//  Fix: store K as [chunk][wk][ks][lane][16B] and V^T as
//  [chunk][h][wk][ks][lane][16B] so every k-loop load is base+lane*16 --
//  one contiguous 1KB wave transaction (8 lines, 100% utilization).
//  Proj K/V stores become contiguous 512B wave-stores too. No swizzles.
//  Mapping (verified algebraically both sides):
//    K frag (wk,ks), lane(ln5,hi): K[t=c*64+wk*32+ln5][d=16ks+8hi+j]
//      addr = c*4096 + wk*2048 + ks*512 + (hi*32+ln5)*8   (bf16 units)
//    proj thread (tt,hh,g,hi_p): d0=hh*32+8g+4hi_p -> ks=2hh+(g>>1),
//      hi_a=g&1, sub=hi_p: addr = tt*2048 + ks*512 + ((g&1)*32+ln5)*8+hi_p*4
//    V frag (h,wk,ks): V^T[hr=h*32+ln5][t=c*64+wk*32+16ks+8hi+j]
//      addr = c*4096 + h*2048 + wk*1024 + ks*512 + (hi*32+ln5)*8
//    proj: t0=tt*32+8g+4hi_p -> addr = hh*2048+tt*1024+(g>>1)*512
//      +((g&1)*32+ln5)*8+hi_p*4
//  Everything else identical to r15 (best: 142.9): zero-LDS/zero-barrier
//  k-loop, T12 in-register softmax, split=4, LB(256,2).

typedef __bf16 bf16;
typedef __bf16 bf16x4 __attribute__((ext_vector_type(4)));
typedef __bf16 bf16x8 __attribute__((ext_vector_type(8)));
typedef float  f32x16 __attribute__((ext_vector_type(16)));

#define MFMA(a, b, c) __builtin_amdgcn_mfma_f32_32x32x16_bf16(a, b, c, 0, 0, 0)

constexpr int T = 4096, D = 1024, HS = 64;
constexpr int ROWS = 4 * T;                   // 16384
constexpr float QSCL = 0.045084220027797f;    // (1/32) * log2(e)

__device__ __forceinline__ void gld16(const void* g, void* l) {
    __builtin_amdgcn_global_load_lds(
        (const __attribute__((address_space(1))) unsigned int*)g,
        (__attribute__((address_space(3))) unsigned int*)l, 16, 0, 0);
}

__device__ inline f32x16 zero16() {
    f32x16 z;
#pragma unroll
    for (int i = 0; i < 16; ++i) z[i] = 0.f;
    return z;
}

// ---- prep: Wt[192][1024] bf16 = concat(Wq^T*QSCL, Wk^T, Wv^T) ----
__global__ __launch_bounds__(256) void prep_wt(
    const float* __restrict__ Wq, const float* __restrict__ Wk,
    const float* __restrict__ Wv, bf16* __restrict__ Wt)
{
    __shared__ float Xf[64 * 68];
    const int m = blockIdx.x >> 4, dt = blockIdx.x & 15;
    const float* W = (m == 0) ? Wq : ((m == 1) ? Wk : Wv);
    const int d0 = dt * 64;
#pragma unroll
    for (int j = 0; j < 4; ++j) {
        int i = threadIdx.x + 256 * j;
        int dr = i >> 4, c4 = i & 15;
        float4 v = *(const float4*)(W + (size_t)(d0 + dr) * 64 + c4 * 4);
        *(float4*)&Xf[dr * 68 + c4 * 4] = v;
    }
    __syncthreads();
    const float scl = (m == 0) ? QSCL : 1.0f;
#pragma unroll
    for (int j = 0; j < 4; ++j) {
        int o = threadIdx.x + 256 * j;
        int h = o >> 4, dc = o & 15;
        bf16x4 w;
#pragma unroll
        for (int k = 0; k < 4; ++k) w[k] = (bf16)(Xf[(dc * 4 + k) * 68 + h] * scl);
        *(bf16x4*)(Wt + (size_t)(m * 64 + h) * D + d0 + dc * 4) = w;
    }
}

// ---- fused projection: grid 256 = 8 xcd x 32 mtile; Q+K+V per block ----
__global__ __launch_bounds__(256) void qkv_proj(
    const float* __restrict__ x, const bf16* __restrict__ Wt,
    bf16* __restrict__ Qg, bf16* __restrict__ Kgt, bf16* __restrict__ Vgt)
{
    __shared__ __align__(16) bf16  Xb[2][64 * 64];   // swizzled granule: [r][u^(r&7)]
    __shared__ __align__(16) short Ws[2][192 * 64];  // swizzled: [h][u^(h&7)]
    const int tid = threadIdx.x;
    const int w = tid >> 6, lane = tid & 63, ln5 = lane & 31, hi = lane >> 5;
    const int tt = w & 1, hh = w >> 1;
    const int xcd = blockIdx.x & 7, mlocal = blockIdx.x >> 3;
    const int r0 = (xcd * 32 + mlocal) * 64;
    const int wb = tid & 448;

    auto stageW = [&](int kc, int buf) {
#pragma unroll
        for (int k2 = 0; k2 < 6; ++k2) {
            int s = k2 * 256 + tid;
            int h = s >> 3, j = s & 7, u = j ^ (h & 7);
            gld16(Wt + (size_t)h * D + kc * 64 + u * 8,
                  &Ws[buf][(k2 * 256 + wb) * 8]);
        }
    };
    float4 xra[2], xrb[2];
    auto stageX_load = [&](int kc) {
#pragma unroll
        for (int k = 0; k < 2; ++k) {
            int e = k * 256 + tid;
            int r = e >> 3, d0 = (e & 7) * 8;
            const float* src = x + (size_t)(r0 + r) * D + kc * 64 + d0;
            xra[k] = *(const float4*)src;
            xrb[k] = *(const float4*)(src + 4);
        }
    };
    auto stageX_write = [&](int buf) {
#pragma unroll
        for (int k = 0; k < 2; ++k) {
            int e = k * 256 + tid;
            int r = e >> 3, d0 = (e & 7) * 8;
            bf16x8 v;
            v[0] = (bf16)xra[k].x; v[1] = (bf16)xra[k].y;
            v[2] = (bf16)xra[k].z; v[3] = (bf16)xra[k].w;
            v[4] = (bf16)xrb[k].x; v[5] = (bf16)xrb[k].y;
            v[6] = (bf16)xrb[k].z; v[7] = (bf16)xrb[k].w;
            *(bf16x8*)&Xb[buf][r * 64 + (((d0 >> 3) ^ (r & 7)) * 8)] = v;
        }
    };

    f32x16 acc0 = zero16(), acc1 = zero16(), acc2 = zero16();
    const int rx = tt * 32 + ln5;
    const int hq = hh * 32 + ln5;
    const int swz = ln5 & 7;

    stageX_load(0); stageW(0, 0); stageX_write(0);
    __syncthreads();
    for (int kc = 0; kc < 16; ++kc) {
        const int cur = kc & 1;
        if (kc < 15) { stageW(kc + 1, cur ^ 1); stageX_load(kc + 1); }
        const bf16*  Xc = &Xb[cur][0];
        const short* Wb = &Ws[cur][0];
#pragma unroll
        for (int ks = 0; ks < 4; ++ks) {
            int g = (ks * 2 + hi) ^ swz;
            bf16x8 fx = *(const bf16x8*)&Xc[rx * 64 + g * 8];
            bf16x8 w0 = *(const bf16x8*)&Wb[(hq)       * 64 + g * 8];
            bf16x8 w1 = *(const bf16x8*)&Wb[(64 + hq)  * 64 + g * 8];
            bf16x8 w2 = *(const bf16x8*)&Wb[(128 + hq) * 64 + g * 8];
            acc0 = MFMA(w0, fx, acc0);   // Q: C^T (col = t)
            acc1 = MFMA(w1, fx, acc1);   // K: C^T (col = t)
            acc2 = MFMA(fx, w2, acc2);   // V: C   (col = h)
        }
        if (kc < 15) stageX_write(cur ^ 1);
        __syncthreads();
    }

    // Q store (linear [t][h]) -- unchanged
    {
        int t = r0 + tt * 32 + ln5;
#pragma unroll
        for (int g = 0; g < 4; ++g) {
            int h0 = hh * 32 + 8 * g + 4 * hi;
            bf16x4 v;
#pragma unroll
            for (int k = 0; k < 4; ++k) v[k] = (bf16)acc0[4 * g + k];
            *(bf16x4*)(Qg + (size_t)t * HS + h0) = v;
        }
    }
    // K store: fragment order [chunk][wk=tt][ks][lane][8bf16]
    //   d0 = hh*32+8g+4hi -> ks = 2hh+(g>>1), hi_a = g&1, sub = hi
    {
        bf16* kdst = Kgt + (size_t)r0 * HS + tt * 2048;
#pragma unroll
        for (int g = 0; g < 4; ++g) {
            bf16x4 v;
#pragma unroll
            for (int k = 0; k < 4; ++k) v[k] = (bf16)acc1[4 * g + k];
            *(bf16x4*)(kdst + (2 * hh + (g >> 1)) * 512 +
                       ((g & 1) * 32 + ln5) * 8 + hi * 4) = v;
        }
    }
    // V store: fragment order [chunk][h=hh][wk=tt][ks][lane][8bf16]
    //   t0 = tt*32+8g+4hi -> ks = g>>1, hi_a = g&1, sub = hi
    {
        bf16* vdst = Vgt + (size_t)r0 * HS + hh * 2048 + tt * 1024;
#pragma unroll
        for (int g = 0; g < 4; ++g) {
            bf16x4 v;
#pragma unroll
            for (int k = 0; k < 4; ++k) v[k] = (bf16)acc2[4 * g + k];
            *(bf16x4*)(vdst + (g >> 1) * 512 +
                       ((g & 1) * 32 + ln5) * 8 + hi * 4) = v;
        }
    }
}

// ---- attention: block = 128 q-rows; wave = 64 q-cols x 32-kr half-chunk ----
// Zero-LDS/zero-barrier k-loop; ALL K/V loads contiguous 1KB wave reads.
__global__ __launch_bounds__(256, 2) void attn(
    const bf16* __restrict__ Qg, const bf16* __restrict__ Kgt,
    const bf16* __restrict__ Vgt, float* __restrict__ Op,
    float* __restrict__ Lp, float* __restrict__ out, int split)
{
    __shared__ __align__(16) short PO[16384];        // 32 KB: epilogue Ox overlay
    __shared__ float Lx[128];

    const int tid = threadIdx.x;
    const int w = tid >> 6, lane = tid & 63, ln5 = lane & 31, hi = lane >> 5;
    const int wq = w & 1, wk = w >> 1;

    int b, qt, half;
    if (split == 4) {
        int rest = blockIdx.x >> 3; qt = rest & 31;
        int combo = (blockIdx.x & 7) + 8 * (rest >> 5);   // (b,half) pinned per XCD
        b = combo >> 2; half = combo & 3;
    } else if (split == 2) {
        int c2 = blockIdx.x & 7; b = c2 >> 1; half = c2 & 1; qt = blockIdx.x >> 3;
    } else { b = blockIdx.x & 3; half = 0; qt = blockIdx.x >> 2; }

    const int rbase = b * T;
    const int seg = T / split;
    const int kb0 = rbase + half * seg;
    const int nc = seg / 64;
    const int qrow0 = rbase + qt * 128 + wq * 64;

    bf16x8 bq[2][4];
    {
        const bf16* qp = Qg + (size_t)(qrow0 + ln5) * HS + hi * 8;
#pragma unroll
        for (int qs = 0; qs < 2; ++qs)
#pragma unroll
            for (int ks = 0; ks < 4; ++ks)
                bq[qs][ks] = *(const bf16x8*)(qp + (size_t)qs * 32 * HS + ks * 16);
    }

    const bf16* Kc = Kgt + (size_t)kb0 * HS;
    const bf16* Vc = Vgt + (size_t)kb0 * HS;

    f32x16 O00 = zero16(), O01 = zero16(), O10 = zero16(), O11 = zero16();
    float l0 = 0.f, l1 = 0.f;

    // fragment-order offsets (bf16 units): all loads are base + lane*8
    const int lane8 = lane * 8;
    const int kbase = wk * 2048 + lane8;             // + ks*512
    const int vb0   = wk * 1024 + lane8;             // h=0: + ks*512
    const int vb1   = 2048 + wk * 1024 + lane8;      // h=1: + ks*512

    bf16x8 kf0 = *(const bf16x8*)(Kc + kbase);
    bf16x8 kf1 = *(const bf16x8*)(Kc + kbase + 512);
    bf16x8 kf2 = *(const bf16x8*)(Kc + kbase + 1024);
    bf16x8 kf3 = *(const bf16x8*)(Kc + kbase + 1536);

    union U8 { unsigned u[4]; bf16x8 v; };

    for (int c = 0; c < nc; ++c) {
        const bf16* Vb = Vc + (size_t)c * 4096;
        bf16x8 v00 = *(const bf16x8*)(Vb + vb0);
        bf16x8 v01 = *(const bf16x8*)(Vb + vb0 + 512);
        bf16x8 v10 = *(const bf16x8*)(Vb + vb1);
        bf16x8 v11 = *(const bf16x8*)(Vb + vb1 + 512);
        const bool pf = (c + 1 < nc);
        bf16x8 kn0, kn1, kn2, kn3;
        if (pf) {
            const bf16* Kn = Kc + (size_t)(c + 1) * 4096;
            kn0 = *(const bf16x8*)(Kn + kbase);
            kn1 = *(const bf16x8*)(Kn + kbase + 512);
            kn2 = *(const bf16x8*)(Kn + kbase + 1024);
            kn3 = *(const bf16x8*)(Kn + kbase + 1536);
        }

        // S^T = K_slice * Q^T  (32 kr x 64 q)
        f32x16 S0 = zero16(), S1 = zero16();
        S0 = MFMA(kf0, bq[0][0], S0); S1 = MFMA(kf0, bq[1][0], S1);
        S0 = MFMA(kf1, bq[0][1], S0); S1 = MFMA(kf1, bq[1][1], S1);
        S0 = MFMA(kf2, bq[0][2], S0); S1 = MFMA(kf2, bq[1][2], S1);
        S0 = MFMA(kf3, bq[0][3], S0); S1 = MFMA(kf3, bq[1][3], S1);

        // no-max softmax; pack P^T to bf16 in-register (T12)
        unsigned wa[8], wbq[8];
#pragma unroll
        for (int g = 0; g < 4; ++g) {
            float p0 = __builtin_amdgcn_exp2f(S0[4 * g + 0]);
            float p1 = __builtin_amdgcn_exp2f(S0[4 * g + 1]);
            float p2 = __builtin_amdgcn_exp2f(S0[4 * g + 2]);
            float p3 = __builtin_amdgcn_exp2f(S0[4 * g + 3]);
            l0 += (p0 + p1) + (p2 + p3);
            asm("v_cvt_pk_bf16_f32 %0, %1, %2" : "=v"(wa[2 * g])     : "v"(p0), "v"(p1));
            asm("v_cvt_pk_bf16_f32 %0, %1, %2" : "=v"(wa[2 * g + 1]) : "v"(p2), "v"(p3));
        }
#pragma unroll
        for (int g = 0; g < 4; ++g) {
            float p0 = __builtin_amdgcn_exp2f(S1[4 * g + 0]);
            float p1 = __builtin_amdgcn_exp2f(S1[4 * g + 1]);
            float p2 = __builtin_amdgcn_exp2f(S1[4 * g + 2]);
            float p3 = __builtin_amdgcn_exp2f(S1[4 * g + 3]);
            l1 += (p0 + p1) + (p2 + p3);
            asm("v_cvt_pk_bf16_f32 %0, %1, %2" : "=v"(wbq[2 * g])     : "v"(p0), "v"(p1));
            asm("v_cvt_pk_bf16_f32 %0, %1, %2" : "=v"(wbq[2 * g + 1]) : "v"(p2), "v"(p3));
        }
#pragma unroll
        for (int j = 0; j < 2; ++j) {
            asm("v_permlane32_swap_b32 %0, %1" : "+v"(wa[j]),      "+v"(wa[j + 2]));
            asm("v_permlane32_swap_b32 %0, %1" : "+v"(wa[4 + j]),  "+v"(wa[6 + j]));
            asm("v_permlane32_swap_b32 %0, %1" : "+v"(wbq[j]),     "+v"(wbq[j + 2]));
            asm("v_permlane32_swap_b32 %0, %1" : "+v"(wbq[4 + j]), "+v"(wbq[6 + j]));
        }
        U8 fa0, fa1, fb0, fb1;
        fa0.u[0] = wa[0];  fa0.u[1] = wa[1];  fa0.u[2] = wa[2];  fa0.u[3] = wa[3];
        fa1.u[0] = wa[4];  fa1.u[1] = wa[5];  fa1.u[2] = wa[6];  fa1.u[3] = wa[7];
        fb0.u[0] = wbq[0]; fb0.u[1] = wbq[1]; fb0.u[2] = wbq[2]; fb0.u[3] = wbq[3];
        fb1.u[0] = wbq[4]; fb1.u[1] = wbq[5]; fb1.u[2] = wbq[6]; fb1.u[3] = wbq[7];

        // O^T += V^T_slice * P^T  (all operands in registers)
        O00 = MFMA(v00, fa0.v, O00);
        O01 = MFMA(v00, fb0.v, O01);
        O10 = MFMA(v10, fa0.v, O10);
        O11 = MFMA(v10, fb0.v, O11);
        O00 = MFMA(v01, fa1.v, O00);
        O01 = MFMA(v01, fb1.v, O01);
        O10 = MFMA(v11, fa1.v, O10);
        O11 = MFMA(v11, fb1.v, O11);

        if (pf) { kf0 = kn0; kf1 = kn1; kf2 = kn2; kf3 = kn3; }
    }

    l0 += __shfl_xor(l0, 32, 64);
    l1 += __shfl_xor(l1, 32, 64);

    // wk-combine through the 32 KB Ox overlay
    __syncthreads();
    float* Ox = (float*)&PO[0];                      // [wq][h 64][q 64]
    if (wk == 1) {
#pragma unroll
        for (int g = 0; g < 4; ++g)
#pragma unroll
            for (int k = 0; k < 4; ++k) {
                int h0 = 8 * g + 4 * hi + k;
                Ox[wq * 4096 + h0 * 64 + ln5]             = O00[4 * g + k];
                Ox[wq * 4096 + h0 * 64 + 32 + ln5]        = O01[4 * g + k];
                Ox[wq * 4096 + (32 + h0) * 64 + ln5]      = O10[4 * g + k];
                Ox[wq * 4096 + (32 + h0) * 64 + 32 + ln5] = O11[4 * g + k];
            }
        if (hi == 0) { Lx[wq * 64 + ln5] = l0; Lx[wq * 64 + 32 + ln5] = l1; }
    }
    __syncthreads();
    if (wk == 0) {
#pragma unroll
        for (int g = 0; g < 4; ++g)
#pragma unroll
            for (int k = 0; k < 4; ++k) {
                int h0 = 8 * g + 4 * hi + k;
                O00[4 * g + k] += Ox[wq * 4096 + h0 * 64 + ln5];
                O01[4 * g + k] += Ox[wq * 4096 + h0 * 64 + 32 + ln5];
                O10[4 * g + k] += Ox[wq * 4096 + (32 + h0) * 64 + ln5];
                O11[4 * g + k] += Ox[wq * 4096 + (32 + h0) * 64 + 32 + ln5];
            }
        l0 += Lx[wq * 64 + ln5];
        l1 += Lx[wq * 64 + 32 + ln5];

        int q0 = qrow0 + ln5, q1 = qrow0 + 32 + ln5;
        if (split == 1) {
            float i0 = 1.0f / l0, i1 = 1.0f / l1;
#pragma unroll
            for (int g = 0; g < 4; ++g) {
                int h0 = 8 * g + 4 * hi;
                float4 o;
                o.x = O00[4*g+0]*i0; o.y = O00[4*g+1]*i0; o.z = O00[4*g+2]*i0; o.w = O00[4*g+3]*i0;
                *(float4*)(out + (size_t)q0 * HS + h0) = o;
                o.x = O01[4*g+0]*i1; o.y = O01[4*g+1]*i1; o.z = O01[4*g+2]*i1; o.w = O01[4*g+3]*i1;
                *(float4*)(out + (size_t)q1 * HS + h0) = o;
                o.x = O10[4*g+0]*i0; o.y = O10[4*g+1]*i0; o.z = O10[4*g+2]*i0; o.w = O10[4*g+3]*i0;
                *(float4*)(out + (size_t)q0 * HS + 32 + h0) = o;
                o.x = O11[4*g+0]*i1; o.y = O11[4*g+1]*i1; o.z = O11[4*g+2]*i1; o.w = O11[4*g+3]*i1;
                *(float4*)(out + (size_t)q1 * HS + 32 + h0) = o;
            }
        } else {
            float* Od = Op + (size_t)half * ROWS * HS;
#pragma unroll
            for (int g = 0; g < 4; ++g) {
                int h0 = 8 * g + 4 * hi;
                float4 o;
                o.x = O00[4*g+0]; o.y = O00[4*g+1]; o.z = O00[4*g+2]; o.w = O00[4*g+3];
                *(float4*)(Od + (size_t)q0 * HS + h0) = o;
                o.x = O01[4*g+0]; o.y = O01[4*g+1]; o.z = O01[4*g+2]; o.w = O01[4*g+3];
                *(float4*)(Od + (size_t)q1 * HS + h0) = o;
                o.x = O10[4*g+0]; o.y = O10[4*g+1]; o.z = O10[4*g+2]; o.w = O10[4*g+3];
                *(float4*)(Od + (size_t)q0 * HS + 32 + h0) = o;
                o.x = O11[4*g+0]; o.y = O11[4*g+1]; o.z = O11[4*g+2]; o.w = O11[4*g+3];
                *(float4*)(Od + (size_t)q1 * HS + 32 + h0) = o;
            }
            if (hi == 0) {
                Lp[half * ROWS + q0] = l0;
                Lp[half * ROWS + q1] = l1;
            }
        }
    }
}

// ---- reduce: out = sum_h(O_h) / sum_h(l_h) ----
__global__ __launch_bounds__(256) void attn_reduce(
    const float* __restrict__ Op, const float* __restrict__ Lp,
    float* __restrict__ out, int split)
{
    int idx = blockIdx.x * 256 + threadIdx.x;        // float4 index
    int row = idx >> 4;
    float4 s; s.x = s.y = s.z = s.w = 0.f;
    float lsum = 0.f;
    for (int h = 0; h < split; ++h) {
        float4 a = *(const float4*)(Op + (size_t)h * ROWS * HS + (size_t)idx * 4);
        s.x += a.x; s.y += a.y; s.z += a.z; s.w += a.w;
        lsum += Lp[h * ROWS + row];
    }
    float inv = 1.0f / lsum;
    s.x *= inv; s.y *= inv; s.z *= inv; s.w *= inv;
    *(float4*)(out + (size_t)idx * 4) = s;
}

extern "C" void kernel_launch(void* const* d_in, const int* in_sizes, int n_in,
                              void* d_out, int out_size, void* d_ws, size_t ws_size,
                              hipStream_t stream)
{
    const float* x  = (const float*)d_in[0];
    const float* Wq = (const float*)d_in[1];
    const float* Wk = (const float*)d_in[2];
    const float* Wv = (const float*)d_in[3];
    float* out = (float*)d_out;

    char* ws = (char*)d_ws;
    bf16* Qg  = (bf16*)(ws);                          // 2 MB  [16384][64]
    bf16* Kgt = (bf16*)(ws + ((size_t)2 << 20));      // 2 MB  fragment-order
    bf16* Vgt = (bf16*)(ws + ((size_t)4 << 20));      // 2 MB  fragment-order
    bf16* Wt  = (bf16*)(ws + ((size_t)6 << 20));      // 384 KB [192][1024]
    float* Lp = (float*)(ws + ((size_t)6 << 20));     // overlays Wt (dead after proj)
    float* Op = (float*)(ws + ((size_t)6 << 20) + ((size_t)1 << 19));

    const size_t base = ((size_t)6 << 20) + ((size_t)1 << 19);
    int split = 1;
    if (ws_size >= base + (size_t)4 * ROWS * HS * sizeof(float)) split = 4;
    else if (ws_size >= base + (size_t)2 * ROWS * HS * sizeof(float)) split = 2;

    prep_wt<<<48, 256, 0, stream>>>(Wq, Wk, Wv, Wt);
    qkv_proj<<<256, 256, 0, stream>>>(x, Wt, Qg, Kgt, Vgt);
    attn<<<128 * split, 256, 0, stream>>>(Qg, Kgt, Vgt, Op, Lp, out, split);
    if (split > 1)
        attn_reduce<<<(ROWS * HS / 4) / 256, 256, 0, stream>>>(Op, Lp, out, split);
}